// Round 1
// baseline (301.376 us; speedup 1.0000x reference)
//
#include <hip/hip_runtime.h>

#define T_LEN 200
#define C_DIM 64
#define PAD   65   // stride 65 floats: bank = (t + c) % 32 -> 2 lanes/bank, conflict-free

__global__ __launch_bounds__(256, 2) void attn_pool_kernel(
    const float* __restrict__ q,     // [B,1,64]
    const float* __restrict__ keys,  // [B,200,64]
    const int*   __restrict__ klen,  // [B,1]
    const float* __restrict__ W,     // [128,1]
    const float* __restrict__ bias,  // [1]
    float* __restrict__ out)         // [B,1,64]
{
    __shared__ float kl[T_LEN * PAD];     // 52000 B keys tile
    __shared__ float Wsh[2 * C_DIM];
    __shared__ float sc[256];             // exp(score) per t
    __shared__ float red[4];
    __shared__ float acc_sh[4][C_DIM];
    __shared__ float qdot_sh;
    __shared__ float scal[2];             // [0]=max, [1]=sumexp

    const int b    = blockIdx.x;
    const int tid  = threadIdx.x;
    const int lane = tid & 63;
    const int wave = tid >> 6;

    if (tid < 2 * C_DIM) Wsh[tid] = W[tid];

    // ---- stage keys[b] (200x64 f32 = 3200 float4) into padded LDS ----
    const float4* kg = reinterpret_cast<const float4*>(keys) + (size_t)b * (T_LEN * C_DIM / 4);
    #pragma unroll
    for (int k = 0; k < 12; ++k) {
        int i = tid + k * 256;
        float4 v = kg[i];
        int e = i << 2;
        int t = e >> 6;
        int c = e & 63;
        float* dst = &kl[t * PAD + c];
        dst[0] = v.x; dst[1] = v.y; dst[2] = v.z; dst[3] = v.w;
    }
    if (tid < 128) {                       // tail: 3200 - 12*256 = 128
        int i = tid + 3072;
        float4 v = kg[i];
        int e = i << 2;
        int t = e >> 6;
        int c = e & 63;
        float* dst = &kl[t * PAD + c];
        dst[0] = v.x; dst[1] = v.y; dst[2] = v.z; dst[3] = v.w;
    }
    __syncthreads();                       // Wsh + kl ready

    // ---- qdot = q[b]·W[0:64] + bias (wave 0, shuffle reduce) ----
    if (wave == 0) {
        float p = q[(size_t)b * C_DIM + lane] * Wsh[lane];
        #pragma unroll
        for (int off = 32; off > 0; off >>= 1)
            p += __shfl_down(p, off, 64);
        if (lane == 0) qdot_sh = p + bias[0];
    }
    __syncthreads();

    // ---- scores: thread t in [0,200) ----
    const int len = klen[b];
    const float MASKV = -4294967295.0f;    // -2^32+1, matches reference
    float myscore = MASKV;
    if (tid < T_LEN) {
        float s = qdot_sh;
        const float* kr = &kl[tid * PAD];
        #pragma unroll
        for (int c = 0; c < C_DIM; ++c) s = fmaf(kr[c], Wsh[C_DIM + c], s);
        float sv = tanhf(s);
        myscore = (tid < len) ? sv : MASKV;
    }

    // ---- block max (4 waves -> red -> scalar) ----
    float v = myscore;
    #pragma unroll
    for (int off = 32; off > 0; off >>= 1)
        v = fmaxf(v, __shfl_down(v, off, 64));
    if (lane == 0) red[wave] = v;
    __syncthreads();
    if (tid == 0) scal[0] = fmaxf(fmaxf(red[0], red[1]), fmaxf(red[2], red[3]));
    __syncthreads();
    const float mx = scal[0];

    // ---- exp + block sum ----
    float e = 0.f;
    if (tid < T_LEN) e = expf(myscore - mx);   // masked: exp(-4.29e9)=0; all-masked: exp(0)=1
    sc[tid] = e;
    float sv = e;
    #pragma unroll
    for (int off = 32; off > 0; off >>= 1)
        sv += __shfl_down(sv, off, 64);
    if (lane == 0) red[wave] = sv;
    __syncthreads();                        // also publishes sc[]
    if (tid == 0) scal[1] = red[0] + red[1] + red[2] + red[3];
    __syncthreads();
    const float inv = 1.0f / scal[1];

    // ---- weighted sum: wave = t-group, lane = channel ----
    float acc = 0.f;
    for (int t = wave; t < T_LEN; t += 4)
        acc = fmaf(sc[t], kl[t * PAD + lane], acc);   // sc[t] broadcast; kl conflict-free
    acc_sh[wave][lane] = acc;
    __syncthreads();
    if (tid < C_DIM) {
        out[(size_t)b * C_DIM + tid] =
            (acc_sh[0][tid] + acc_sh[1][tid] + acc_sh[2][tid] + acc_sh[3][tid]) * inv;
    }
}

extern "C" void kernel_launch(void* const* d_in, const int* in_sizes, int n_in,
                              void* d_out, int out_size, void* d_ws, size_t ws_size,
                              hipStream_t stream) {
    const float* q    = (const float*)d_in[0];
    const float* keys = (const float*)d_in[1];
    const int*   klen = (const int*)d_in[2];
    const float* W    = (const float*)d_in[3];
    const float* bias = (const float*)d_in[4];
    float* out = (float*)d_out;
    const int B = in_sizes[0] / C_DIM;   // 4096
    attn_pool_kernel<<<B, 256, 0, stream>>>(q, keys, klen, W, bias, out);
}

// Round 2
// 292.266 us; speedup vs baseline: 1.0312x; 1.0312x over previous
//
#include <hip/hip_runtime.h>

#define T_LEN 200
#define C_DIM 64
#define NF4   (T_LEN * C_DIM / 4)   // 3200 float4 per batch row

#define AS1 __attribute__((address_space(1)))
#define AS3 __attribute__((address_space(3)))

// LDS tile layout: row t, float4-slot p holds source float4 (p ^ (t&15)) of that row.
// -> read slot (g ^ (t&15)) to get channels [4g,4g+4). XOR makes ds_read_b128 of
//    "lane = row" hit all 8 bank-quads evenly (b128 floor), and the per-t b32 reads
//    in the weighted-sum phase stay 2 lanes/bank (free).

__global__ __launch_bounds__(256, 3) void attn_pool_kernel(
    const float* __restrict__ q,     // [B,1,64]
    const float* __restrict__ keys,  // [B,200,64]
    const int*   __restrict__ klen,  // [B,1]
    const float* __restrict__ W,     // [128,1]
    const float* __restrict__ bias,  // [1]
    float* __restrict__ out)         // [B,1,64]
{
    __shared__ float kl[T_LEN * C_DIM];   // 51200 B, swizzled, unpadded (LDS-DMA needs linear dest)
    __shared__ float sc[T_LEN];           // exp(score)
    __shared__ float red[4];              // per-wave partial sums
    __shared__ float acc_sh[4][C_DIM];
    __shared__ float qdot_sh;

    const int tid  = threadIdx.x;
    const int lane = tid & 63;
    const int wave = tid >> 6;
    const int b    = blockIdx.x;

    const float4* kg = reinterpret_cast<const float4*>(keys) + (size_t)b * NF4;

    // ---- stage keys[b] via LDS-DMA: linear LDS dest, swizzled global source ----
    // dest f4 index i = base + lane (base wave-uniform); src f4 = (i&~15) | ((i&15)^((i>>4)&15))
    #pragma unroll
    for (int k = 0; k < 12; ++k) {
        const int base = k * 256 + wave * 64;              // uniform per wave
        const int i    = base + lane;
        const int src  = (i & ~15) | ((i & 15) ^ ((i >> 4) & 15));
        __builtin_amdgcn_global_load_lds((const AS1 void*)(kg + src),
                                         (AS3 void*)&kl[base * 4], 16, 0, 0);
    }
    if (wave < 2) {                                        // tail: 3200 - 3072 = 128 f4
        const int base = 3072 + wave * 64;
        const int i    = base + lane;
        const int src  = (i & ~15) | ((i & 15) ^ ((i >> 4) & 15));
        __builtin_amdgcn_global_load_lds((const AS1 void*)(kg + src),
                                         (AS3 void*)&kl[base * 4], 16, 0, 0);
    }

    // ---- qdot = q[b]·W[0:64] + bias, overlapped with the in-flight DMA (wave 0) ----
    if (wave == 0) {
        float p = q[(size_t)b * C_DIM + lane] * W[lane];
        #pragma unroll
        for (int off = 32; off > 0; off >>= 1)
            p += __shfl_down(p, off, 64);
        if (lane == 0) qdot_sh = p + bias[0];
    }
    __syncthreads();                                       // kl + qdot ready

    // ---- score for row t = tid (t < 200); tanh in [-1,1] => no max-subtraction needed ----
    const int len = klen[b];
    float e = 0.0f;
    if (tid < T_LEN) {
        float s = qdot_sh;
        const float4* klf4 = reinterpret_cast<const float4*>(kl);
        const int x = tid & 15;
        #pragma unroll
        for (int g = 0; g < 16; ++g) {                     // ds_read_b128, conflict-free via XOR
            float4 v = klf4[tid * 16 + (g ^ x)];
            const int c = 4 * g;                           // uniform -> W2 from scalar loads
            s = fmaf(v.x, W[C_DIM + c + 0], s);
            s = fmaf(v.y, W[C_DIM + c + 1], s);
            s = fmaf(v.z, W[C_DIM + c + 2], s);
            s = fmaf(v.w, W[C_DIM + c + 3], s);
        }
        const float sv = tanhf(s);
        if (len == 0)       e = 1.0f;                      // softmax of all-masked row = uniform
        else if (tid < len) e = __expf(sv);                // masked lanes keep e = 0
        sc[tid] = e;
    }

    // ---- block sum of e (threads >= 200 contribute 0) ----
    float svs = e;
    #pragma unroll
    for (int off = 32; off > 0; off >>= 1)
        svs += __shfl_down(svs, off, 64);
    if (lane == 0) red[wave] = svs;
    __syncthreads();                                       // publishes sc[] + red[]
    const float inv = 1.0f / (red[0] + red[1] + red[2] + red[3]);

    // ---- weighted sum: lane = channel, wave owns t in [wave*50, wave*50+50) ----
    float acc = 0.0f;
    const int c = lane;
    #pragma unroll 10
    for (int j = 0; j < 50; ++j) {
        const int t = wave * 50 + j;
        const float w = sc[t];                             // broadcast read
        const int p = (c >> 2) ^ (t & 15);
        acc = fmaf(w, kl[t * 64 + p * 4 + (c & 3)], acc);  // 2 lanes/bank: free
    }
    acc_sh[wave][c] = acc;
    __syncthreads();
    if (tid < C_DIM) {
        out[(size_t)b * C_DIM + tid] =
            (acc_sh[0][tid] + acc_sh[1][tid] + acc_sh[2][tid] + acc_sh[3][tid]) * inv;
    }
}

extern "C" void kernel_launch(void* const* d_in, const int* in_sizes, int n_in,
                              void* d_out, int out_size, void* d_ws, size_t ws_size,
                              hipStream_t stream) {
    const float* q    = (const float*)d_in[0];
    const float* keys = (const float*)d_in[1];
    const int*   klen = (const int*)d_in[2];
    const float* W    = (const float*)d_in[3];
    const float* bias = (const float*)d_in[4];
    float* out = (float*)d_out;
    const int B = in_sizes[0] / C_DIM;   // 4096
    attn_pool_kernel<<<B, 256, 0, stream>>>(q, keys, klen, W, bias, out);
}